// Round 4
// baseline (1698.131 us; speedup 1.0000x reference)
//
#include <hip/hip_runtime.h>

// DRL4SSP pointer-network decoder, MI355X (gfx950).
// 64 batches -> 64 blocks x 512 threads, 127 sequential steps, 7 barriers/step.
// base1/base2/Wcomb/static in LDS (161 KB); Whh/w1h/w2d/static_h fragments in
// registers (launch_bounds(512,1) -> 256-VGPR budget, no spills). Zero global
// or scratch traffic inside the step loop.

namespace {

constexpr int kB = 64, kSS = 8, kDS = 4, kH = 128, kS = 128, kT = 127, kG3 = 384;

// workspace layout (float offsets)
constexpr size_t OFF_BASE1 = 0;
constexpr size_t OFF_BASE2 = OFF_BASE1 + (size_t)kB * kH * kS;
constexpr size_t OFF_SHG   = OFF_BASE2 + (size_t)kB * kH * kS;
constexpr size_t OFF_DHG   = OFF_SHG   + (size_t)kB * kH * kS;
constexpr size_t OFF_SHT   = OFF_DHG   + (size_t)kB * kH * kS;
constexpr size_t OFF_WCT   = OFF_SHT   + (size_t)kB * kS * kH;  // WcombT [8][384]
constexpr size_t OFF_BCOMB = OFF_WCT   + (size_t)kSS * kG3;
constexpr size_t OFF_W1HT  = OFF_BCOMB + (size_t)kG3;
constexpr size_t OFF_W2DT  = OFF_W1HT  + (size_t)kH * kH;
// total = OFF_W2DT + kH*kH = 5,279,104 floats (~21.1 MB)

// dynamic-LDS layout (float offsets)
constexpr int L_BASE1 = 0;        // 16384
constexpr int L_BASE2 = 16384;    // 16384
constexpr int L_WCT   = 32768;    // 3072
constexpr int L_BC    = 35840;    // 384
constexpr int L_BH    = 36224;    // 384
constexpr int L_STAT  = 36608;    // 1024
constexpr int L_PG    = 37632;    // 1536  [seg][gate][128]
constexpr int L_PU    = 39168;    // 512
constexpr int L_PA    = 39680;    // 512
constexpr int L_MASK  = 40192;    // 128
constexpr int L_DEC   = 40320;    // 8
constexpr int L_WSUM  = 40328;    // 4
constexpr int L_RINV  = 40332;    // 1
constexpr int LDS_FLOATS = 40336;
constexpr int LDS_BYTES  = LDS_FLOATS * 4;  // 161,344 <= 163,840

__device__ __forceinline__ float rlane(float v, int l) {
  return __uint_as_float(__builtin_amdgcn_readlane(__float_as_uint(v), (unsigned)l));
}

__device__ __forceinline__ float tanh_fast(float x) {
  // identical to the round-1/2 (passing) formula — trajectory-sensitive
  x = fminf(15.f, fmaxf(-15.f, x));
  float e = __expf(-2.f * x);
  return (1.f - e) * __builtin_amdgcn_rcpf(1.f + e);
}

// ---------------- precompute kernels ----------------

__global__ void prep_w(const float* __restrict__ W_ih, const float* __restrict__ W_dec,
                       const float* __restrict__ b_ih, const float* __restrict__ b_dec,
                       const float* __restrict__ ww1, const float* __restrict__ ww2,
                       float* __restrict__ ws) {
  const int tid = threadIdx.x;
  float* WcT  = ws + OFF_WCT;    // [i][j] = sum_k W_ih[j,k] W_dec[k,i]
  float* bcomb = ws + OFF_BCOMB;
  float* w1hT  = ws + OFF_W1HT;
  float* w2dT  = ws + OFF_W2DT;
  for (int idx = tid; idx < kSS * kG3; idx += 256) {
    int i = idx / kG3, j = idx % kG3;
    float acc = 0.f;
    for (int k = 0; k < kH; ++k) acc = fmaf(W_ih[j * kH + k], W_dec[k * kSS + i], acc);
    WcT[idx] = acc;
  }
  for (int j = tid; j < kG3; j += 256) {
    float acc = b_ih[j];
    for (int k = 0; k < kH; ++k) acc = fmaf(W_ih[j * kH + k], b_dec[k], acc);
    bcomb[j] = acc;
  }
  for (int idx = tid; idx < kH * kH; idx += 256) {
    int k = idx >> 7, h = idx & 127;
    w1hT[idx] = ww1[h * kG3 + 2 * kH + k];  // w1h = ww1[:, 2H:3H]
    w2dT[idx] = ww2[h * kG3 + kH + k];      // w2d = ww2[:, H:2H]
  }
}

__global__ void prep_sh(const float* __restrict__ stat_g, const float* __restrict__ dyn_g,
                        const float* __restrict__ W_s, const float* __restrict__ b_s,
                        const float* __restrict__ W_d, const float* __restrict__ b_d,
                        float* __restrict__ ws) {
  const int b = blockIdx.x, tid = threadIdx.x;
  float* sh_g = ws + OFF_SHG;
  float* dh_g = ws + OFF_DHG;
  float* shT  = ws + OFF_SHT;
  const float* sb = stat_g + (size_t)b * kSS * kS;
  const float* db = dyn_g + (size_t)b * kDS * kS;
  for (int idx = tid; idx < kH * kS; idx += 256) {
    int k = idx >> 7, s = idx & 127;
    float acc = b_s[k];
#pragma unroll
    for (int i = 0; i < kSS; ++i) acc = fmaf(W_s[k * kSS + i], sb[i * kS + s], acc);
    sh_g[(size_t)b * kH * kS + idx] = acc;
    float accd = b_d[k];
#pragma unroll
    for (int i = 0; i < kDS; ++i) accd = fmaf(W_d[k * kDS + i], db[i * kS + s], accd);
    dh_g[(size_t)b * kH * kS + idx] = accd;
  }
  for (int idx = tid; idx < kS * kH; idx += 256) {
    int s = idx >> 7, k = idx & 127;
    float acc = b_s[k];
#pragma unroll
    for (int i = 0; i < kSS; ++i) acc = fmaf(W_s[k * kSS + i], sb[i * kS + s], acc);
    shT[(size_t)b * kS * kH + idx] = acc;
  }
}

__global__ void prep_base(const float* __restrict__ ww1, const float* __restrict__ ww2,
                          float* __restrict__ ws) {
  const int b = blockIdx.x, which = blockIdx.y, tid = threadIdx.x;
  const float* sh_g = ws + OFF_SHG + (size_t)b * kH * kS;
  const float* dh_g = ws + OFF_DHG + (size_t)b * kH * kS;
  const float* ww = which ? ww2 : ww1;
  const int dh_off = which ? 2 * kH : kH;
  float* dst = ws + (which ? OFF_BASE2 : OFF_BASE1) + (size_t)b * kH * kS;
  for (int idx = tid; idx < kH * kS / 4; idx += 256) {
    int h = idx >> 5, sq = idx & 31;
    const float* wrow = ww + h * kG3;
    float4 acc = make_float4(0.f, 0.f, 0.f, 0.f);
#pragma unroll 8
    for (int k = 0; k < kH; ++k) {
      float w = wrow[k];
      float4 v = *reinterpret_cast<const float4*>(sh_g + k * kS + sq * 4);
      acc.x = fmaf(w, v.x, acc.x); acc.y = fmaf(w, v.y, acc.y);
      acc.z = fmaf(w, v.z, acc.z); acc.w = fmaf(w, v.w, acc.w);
    }
#pragma unroll 8
    for (int k = 0; k < kH; ++k) {
      float w = wrow[dh_off + k];
      float4 v = *reinterpret_cast<const float4*>(dh_g + k * kS + sq * 4);
      acc.x = fmaf(w, v.x, acc.x); acc.y = fmaf(w, v.y, acc.y);
      acc.z = fmaf(w, v.z, acc.z); acc.w = fmaf(w, v.w, acc.w);
    }
    *reinterpret_cast<float4*>(dst + h * kS + sq * 4) = acc;
  }
}

// ---------------- main sequential kernel ----------------

__global__ __launch_bounds__(512, 1) void ptrnet_main(
    const float* __restrict__ stat_g, const float* __restrict__ dyn_g,
    const float* __restrict__ vv1_g, const float* __restrict__ vv2_g,
    const float* __restrict__ bhh_g, const float* __restrict__ Whh_g,
    const float* __restrict__ ws, float* __restrict__ out) {
  extern __shared__ float sm[];
  const int b = blockIdx.x;
  const int tid = threadIdx.x;
  const int hh = tid & 127;          // output/s index
  const int seg = tid >> 7;          // 0..3: 32-wide k/h chunk
  const int lane = tid & 63;
  const int li = seg * 32 + (hh & 31);  // this thread's "owned" 128-index

  float* base1_l = sm + L_BASE1;
  float* base2_l = sm + L_BASE2;
  float* wct_l   = sm + L_WCT;
  float* bc_l    = sm + L_BC;
  float* bh_l    = sm + L_BH;
  float* stat_l  = sm + L_STAT;
  float* pg_l    = sm + L_PG;
  float* pu_l    = sm + L_PU;
  float* pa_l    = sm + L_PA;
  float* mask_l  = sm + L_MASK;
  float* dec_l   = sm + L_DEC;
  float* wsum_l  = sm + L_WSUM;
  float* rinv_l  = sm + L_RINV;

  // ---- LDS init (one-time) ----
  {
    const float4* b1g = reinterpret_cast<const float4*>(ws + OFF_BASE1 + (size_t)b * kH * kS);
    const float4* b2g = reinterpret_cast<const float4*>(ws + OFF_BASE2 + (size_t)b * kH * kS);
    float4* b1l = reinterpret_cast<float4*>(base1_l);
    float4* b2l = reinterpret_cast<float4*>(base2_l);
    for (int i = tid; i < kH * kS / 4; i += 512) { b1l[i] = b1g[i]; b2l[i] = b2g[i]; }
    for (int i = tid; i < kSS * kG3; i += 512) wct_l[i] = ws[OFF_WCT + i];
    if (tid < kG3) { bc_l[tid] = ws[OFF_BCOMB + tid]; bh_l[tid] = bhh_g[tid]; }
    for (int i = tid; i < kSS * kS; i += 512) stat_l[i] = stat_g[(size_t)b * kSS * kS + i];
    if (tid < kS)
      mask_l[tid] = (tid == 0 || dyn_g[(size_t)b * kDS * kS + tid] != 0.f) ? 0.f : 1.f;
    if (tid < kSS) dec_l[tid] = 0.f;
  }

  // ---- persistent register caches (~232 VGPRs incl. working set) ----
  float w1r[32], w2r[32], shr[32];
  {
    const float* w1hT = ws + OFF_W1HT;
    const float* w2dT = ws + OFF_W2DT;
    const float* shT  = ws + OFF_SHT + (size_t)b * kS * kH;
#pragma unroll
    for (int kk = 0; kk < 32; ++kk) {
      int row = seg * 32 + kk;
      w1r[kk] = w1hT[row * kH + hh];
      w2r[kk] = w2dT[row * kH + hh];
      shr[kk] = shT[row * kH + hh];
    }
  }
  float whr0[32], whr1[32], whr2[32];
#pragma unroll
  for (int q = 0; q < 8; ++q) {
    float4 a0 = *reinterpret_cast<const float4*>(Whh_g + (0 * kH + hh) * kH + seg * 32 + q * 4);
    float4 a1 = *reinterpret_cast<const float4*>(Whh_g + (1 * kH + hh) * kH + seg * 32 + q * 4);
    float4 a2 = *reinterpret_cast<const float4*>(Whh_g + (2 * kH + hh) * kH + seg * 32 + q * 4);
    whr0[q*4+0]=a0.x; whr0[q*4+1]=a0.y; whr0[q*4+2]=a0.z; whr0[q*4+3]=a0.w;
    whr1[q*4+0]=a1.x; whr1[q*4+1]=a1.y; whr1[q*4+2]=a1.z; whr1[q*4+3]=a1.w;
    whr2[q*4+0]=a2.x; whr2[q*4+1]=a2.y; whr2[q*4+2]=a2.z; whr2[q*4+3]=a2.w;
  }
  float v_vv1 = vv1_g[li], v_vv2 = vv2_g[li];
  float h_prev = 0.f;
  __syncthreads();

  for (int t = 0; t < kT; ++t) {
    // ---- PH_A: gi (own li, kept in regs) + gh partials ----
    float gi0, gi1, gi2;
    {
      float v_dec = dec_l[lane & 7];
      gi0 = bc_l[li]; gi1 = bc_l[kH + li]; gi2 = bc_l[2 * kH + li];
#pragma unroll
      for (int i = 0; i < 8; ++i) {
        float d = rlane(v_dec, i);
        gi0 = fmaf(wct_l[i * kG3 + li], d, gi0);
        gi1 = fmaf(wct_l[i * kG3 + kH + li], d, gi1);
        gi2 = fmaf(wct_l[i * kG3 + 2 * kH + li], d, gi2);
      }
      float a0 = 0.f, a1 = 0.f, a2 = 0.f;
#pragma unroll
      for (int kk = 0; kk < 32; ++kk) {
        float hv = rlane(h_prev, kk);
        a0 = fmaf(whr0[kk], hv, a0);
        a1 = fmaf(whr1[kk], hv, a1);
        a2 = fmaf(whr2[kk], hv, a2);
      }
      pg_l[(seg * 3 + 0) * kS + hh] = a0;
      pg_l[(seg * 3 + 1) * kS + hh] = a1;
      pg_l[(seg * 3 + 2) * kS + hh] = a2;
    }
    __syncthreads();

    // ---- PH_B: GRU (replicated per-thread for own li) + u1 partials ----
    {
      float gh0 = bh_l[li] +
          ((pg_l[(0*3+0)*kS+li] + pg_l[(1*3+0)*kS+li]) + (pg_l[(2*3+0)*kS+li] + pg_l[(3*3+0)*kS+li]));
      float gh1 = bh_l[kH + li] +
          ((pg_l[(0*3+1)*kS+li] + pg_l[(1*3+1)*kS+li]) + (pg_l[(2*3+1)*kS+li] + pg_l[(3*3+1)*kS+li]));
      float gh2 = bh_l[2*kH + li] +
          ((pg_l[(0*3+2)*kS+li] + pg_l[(1*3+2)*kS+li]) + (pg_l[(2*3+2)*kS+li] + pg_l[(3*3+2)*kS+li]));
      float r = 1.f / (1.f + __expf(-(gi0 + gh0)));
      float z = 1.f / (1.f + __expf(-(gi1 + gh1)));
      float x = gi2 + r * gh2;
      x = fminf(15.f, fmaxf(-15.f, x));
      float e = __expf(-2.f * x);
      float n = (1.f - e) / (1.f + e);
      float hnew = (1.f - z) * n + z * h_prev;
      h_prev = hnew;
      float acc0 = 0.f, acc1 = 0.f;
#pragma unroll
      for (int kk = 0; kk < 16; ++kk) {
        acc0 = fmaf(rlane(hnew, 2 * kk), w1r[2 * kk], acc0);
        acc1 = fmaf(rlane(hnew, 2 * kk + 1), w1r[2 * kk + 1], acc1);
      }
      pu_l[seg * kS + hh] = acc0 + acc1;
    }
    __syncthreads();

    // ---- PH_C: attn1 partials (tanh over 32 h-rows) ----
    {
      float v_u1 = (pu_l[li] + pu_l[kS + li]) + (pu_l[2*kS + li] + pu_l[3*kS + li]);
      float acc0 = 0.f, acc1 = 0.f;
#pragma unroll
      for (int kk = 0; kk < 16; ++kk) {
        float xa = base1_l[(seg * 32 + 2*kk) * kS + hh] + rlane(v_u1, 2*kk);
        float xb = base1_l[(seg * 32 + 2*kk+1) * kS + hh] + rlane(v_u1, 2*kk+1);
        acc0 = fmaf(rlane(v_vv1, 2*kk), tanh_fast(xa), acc0);
        acc1 = fmaf(rlane(v_vv1, 2*kk+1), tanh_fast(xb), acc1);
      }
      pa_l[seg * kS + hh] = acc0 + acc1;
    }
    __syncthreads();

    // ---- PH_E: softmax1 exp (no max-sub) + chunk sums + dytext partials ----
    {
      float a = (pa_l[li] + pa_l[kS + li]) + (pa_l[2*kS + li] + pa_l[3*kS + li]);
      float ee = __expf(fminf(a, 60.f));
      float ssum = ee;
#pragma unroll
      for (int off = 1; off < 32; off <<= 1) ssum += __shfl_xor(ssum, off);
      if ((lane & 31) == 0) wsum_l[seg] = ssum;
      float acc0 = 0.f, acc1 = 0.f;
#pragma unroll
      for (int kk = 0; kk < 16; ++kk) {
        acc0 = fmaf(rlane(ee, 2 * kk), shr[2 * kk], acc0);
        acc1 = fmaf(rlane(ee, 2 * kk + 1), shr[2 * kk + 1], acc1);
      }
      pu_l[seg * kS + hh] = acc0 + acc1;
    }
    __syncthreads();

    // ---- PH_F: u2 partials; one thread computes 1/sum ----
    {
      float v_dy = (pu_l[li] + pu_l[kS + li]) + (pu_l[2*kS + li] + pu_l[3*kS + li]);
      float acc0 = 0.f, acc1 = 0.f;
#pragma unroll
      for (int kk = 0; kk < 16; ++kk) {
        acc0 = fmaf(rlane(v_dy, 2 * kk), w2r[2 * kk], acc0);
        acc1 = fmaf(rlane(v_dy, 2 * kk + 1), w2r[2 * kk + 1], acc1);
      }
      pa_l[seg * kS + hh] = acc0 + acc1;
      if (tid == 0) rinv_l[0] = 1.0f / ((wsum_l[0] + wsum_l[1]) + (wsum_l[2] + wsum_l[3]));
    }
    __syncthreads();

    // ---- PH_G: attn2 partials (tanh over 32 h-rows) ----
    {
      float rin = rinv_l[0];
      float v_u2 = ((pa_l[li] + pa_l[kS + li]) + (pa_l[2*kS + li] + pa_l[3*kS + li])) * rin;
      float acc0 = 0.f, acc1 = 0.f;
#pragma unroll
      for (int kk = 0; kk < 16; ++kk) {
        float xa = base2_l[(seg * 32 + 2*kk) * kS + hh] + rlane(v_u2, 2*kk);
        float xb = base2_l[(seg * 32 + 2*kk+1) * kS + hh] + rlane(v_u2, 2*kk+1);
        acc0 = fmaf(rlane(v_vv2, 2*kk), tanh_fast(xa), acc0);
        acc1 = fmaf(rlane(v_vv2, 2*kk+1), tanh_fast(xb), acc1);
      }
      pu_l[seg * kS + hh] = acc0 + acc1;
    }
    __syncthreads();

    // ---- PH_H: logits, argmax, logsumexp, state update (wave 0 only) ----
    if (tid < 64) {
      int s0 = lane, s1 = lane + 64;
      float l0 = (pu_l[s0] + pu_l[kS + s0]) + (pu_l[2*kS + s0] + pu_l[3*kS + s0]);
      float l1 = (pu_l[s1] + pu_l[kS + s1]) + (pu_l[2*kS + s1] + pu_l[3*kS + s1]);
      l0 += (mask_l[s0] > 0.f ? 0.f : -1e30f);
      l1 += (mask_l[s1] > 0.f ? 0.f : -1e30f);
      float es = __expf(l0) + __expf(l1);
      float mv; int mi;
      if (l1 > l0) { mv = l1; mi = s1; } else { mv = l0; mi = s0; }
#pragma unroll
      for (int off = 1; off < 64; off <<= 1) {
        float ov = __shfl_xor(mv, off);
        int oi = __shfl_xor(mi, off);
        if (ov > mv || (ov == mv && oi < mi)) { mv = ov; mi = oi; }
        es += __shfl_xor(es, off);
      }
      if (lane == 0) {
        out[b * kT + t] = (float)mi;
        out[kB * kT + b * kT + t] = mv - __logf(es);
        mask_l[mi] = 0.f;
      }
      if (lane < kSS) dec_l[lane] = stat_l[lane * kS + mi];
    }
    __syncthreads();
  }
}

}  // namespace

extern "C" void kernel_launch(void* const* d_in, const int* in_sizes, int n_in,
                              void* d_out, int out_size, void* d_ws, size_t ws_size,
                              hipStream_t stream) {
  const float* stat_g = (const float*)d_in[0];
  const float* dyn_g  = (const float*)d_in[1];
  const float* W_s   = (const float*)d_in[3];
  const float* b_s   = (const float*)d_in[4];
  const float* W_d   = (const float*)d_in[5];
  const float* b_d   = (const float*)d_in[6];
  const float* W_dec = (const float*)d_in[7];
  const float* b_dec = (const float*)d_in[8];
  const float* vv1   = (const float*)d_in[9];
  const float* ww1   = (const float*)d_in[10];
  const float* vv2   = (const float*)d_in[11];
  const float* ww2   = (const float*)d_in[12];
  const float* W_ih  = (const float*)d_in[13];
  const float* W_hh  = (const float*)d_in[14];
  const float* b_ih  = (const float*)d_in[15];
  const float* b_hh  = (const float*)d_in[16];

  float* ws = (float*)d_ws;
  float* out = (float*)d_out;

  hipFuncSetAttribute(reinterpret_cast<const void*>(ptrnet_main),
                      hipFuncAttributeMaxDynamicSharedMemorySize, LDS_BYTES);

  prep_w<<<1, 256, 0, stream>>>(W_ih, W_dec, b_ih, b_dec, ww1, ww2, ws);
  prep_sh<<<kB, 256, 0, stream>>>(stat_g, dyn_g, W_s, b_s, W_d, b_d, ws);
  prep_base<<<dim3(kB, 2), 256, 0, stream>>>(ww1, ww2, ws);
  ptrnet_main<<<kB, 512, LDS_BYTES, stream>>>(stat_g, dyn_g, vv1, vv2, b_hh, W_hh, ws, out);
}

// Round 5
// 1695.682 us; speedup vs baseline: 1.0014x; 1.0014x over previous
//
#include <hip/hip_runtime.h>

// DRL4SSP pointer-network decoder, MI355X (gfx950).
// 64 batches -> 64 blocks x 512 threads, 127 sequential steps, 7 barriers/step.
// base1/base2/Wcomb/static in LDS (161 KB); Whh/w1h/w2d/static_h fragments in
// registers. amdgpu_waves_per_eu(2) pins the allocator to a 256-VGPR budget
// (2 waves/EU = exactly one resident 512-thread block) so nothing spills.

namespace {

constexpr int kB = 64, kSS = 8, kDS = 4, kH = 128, kS = 128, kT = 127, kG3 = 384;

// workspace layout (float offsets)
constexpr size_t OFF_BASE1 = 0;
constexpr size_t OFF_BASE2 = OFF_BASE1 + (size_t)kB * kH * kS;
constexpr size_t OFF_SHG   = OFF_BASE2 + (size_t)kB * kH * kS;
constexpr size_t OFF_DHG   = OFF_SHG   + (size_t)kB * kH * kS;
constexpr size_t OFF_SHT   = OFF_DHG   + (size_t)kB * kH * kS;
constexpr size_t OFF_WCT   = OFF_SHT   + (size_t)kB * kS * kH;  // WcombT [8][384]
constexpr size_t OFF_BCOMB = OFF_WCT   + (size_t)kSS * kG3;
constexpr size_t OFF_W1HT  = OFF_BCOMB + (size_t)kG3;
constexpr size_t OFF_W2DT  = OFF_W1HT  + (size_t)kH * kH;
// total = OFF_W2DT + kH*kH = 5,279,104 floats (~21.1 MB)

// dynamic-LDS layout (float offsets)
constexpr int L_BASE1 = 0;        // 16384
constexpr int L_BASE2 = 16384;    // 16384
constexpr int L_WCT   = 32768;    // 3072
constexpr int L_BC    = 35840;    // 384
constexpr int L_BH    = 36224;    // 384
constexpr int L_STAT  = 36608;    // 1024
constexpr int L_PG    = 37632;    // 1536  [seg][gate][128]
constexpr int L_PU    = 39168;    // 512
constexpr int L_PA    = 39680;    // 512
constexpr int L_MASK  = 40192;    // 128
constexpr int L_DEC   = 40320;    // 8
constexpr int L_WSUM  = 40328;    // 4
constexpr int L_RINV  = 40332;    // 1
constexpr int LDS_FLOATS = 40336;
constexpr int LDS_BYTES  = LDS_FLOATS * 4;  // 161,344 <= 163,840

__device__ __forceinline__ float rlane(float v, int l) {
  return __uint_as_float(__builtin_amdgcn_readlane(__float_as_uint(v), (unsigned)l));
}

__device__ __forceinline__ float tanh_fast(float x) {
  // identical to the round-1/2/4 (passing) formula — trajectory-sensitive
  x = fminf(15.f, fmaxf(-15.f, x));
  float e = __expf(-2.f * x);
  return (1.f - e) * __builtin_amdgcn_rcpf(1.f + e);
}

// ---------------- precompute kernels ----------------

__global__ void prep_w(const float* __restrict__ W_ih, const float* __restrict__ W_dec,
                       const float* __restrict__ b_ih, const float* __restrict__ b_dec,
                       const float* __restrict__ ww1, const float* __restrict__ ww2,
                       float* __restrict__ ws) {
  const int tid = threadIdx.x;
  float* WcT  = ws + OFF_WCT;    // [i][j] = sum_k W_ih[j,k] W_dec[k,i]
  float* bcomb = ws + OFF_BCOMB;
  float* w1hT  = ws + OFF_W1HT;
  float* w2dT  = ws + OFF_W2DT;
  for (int idx = tid; idx < kSS * kG3; idx += 256) {
    int i = idx / kG3, j = idx % kG3;
    float acc = 0.f;
    for (int k = 0; k < kH; ++k) acc = fmaf(W_ih[j * kH + k], W_dec[k * kSS + i], acc);
    WcT[idx] = acc;
  }
  for (int j = tid; j < kG3; j += 256) {
    float acc = b_ih[j];
    for (int k = 0; k < kH; ++k) acc = fmaf(W_ih[j * kH + k], b_dec[k], acc);
    bcomb[j] = acc;
  }
  for (int idx = tid; idx < kH * kH; idx += 256) {
    int k = idx >> 7, h = idx & 127;
    w1hT[idx] = ww1[h * kG3 + 2 * kH + k];  // w1h = ww1[:, 2H:3H]
    w2dT[idx] = ww2[h * kG3 + kH + k];      // w2d = ww2[:, H:2H]
  }
}

__global__ void prep_sh(const float* __restrict__ stat_g, const float* __restrict__ dyn_g,
                        const float* __restrict__ W_s, const float* __restrict__ b_s,
                        const float* __restrict__ W_d, const float* __restrict__ b_d,
                        float* __restrict__ ws) {
  const int b = blockIdx.x, tid = threadIdx.x;
  float* sh_g = ws + OFF_SHG;
  float* dh_g = ws + OFF_DHG;
  float* shT  = ws + OFF_SHT;
  const float* sb = stat_g + (size_t)b * kSS * kS;
  const float* db = dyn_g + (size_t)b * kDS * kS;
  for (int idx = tid; idx < kH * kS; idx += 256) {
    int k = idx >> 7, s = idx & 127;
    float acc = b_s[k];
#pragma unroll
    for (int i = 0; i < kSS; ++i) acc = fmaf(W_s[k * kSS + i], sb[i * kS + s], acc);
    sh_g[(size_t)b * kH * kS + idx] = acc;
    float accd = b_d[k];
#pragma unroll
    for (int i = 0; i < kDS; ++i) accd = fmaf(W_d[k * kDS + i], db[i * kS + s], accd);
    dh_g[(size_t)b * kH * kS + idx] = accd;
  }
  for (int idx = tid; idx < kS * kH; idx += 256) {
    int s = idx >> 7, k = idx & 127;
    float acc = b_s[k];
#pragma unroll
    for (int i = 0; i < kSS; ++i) acc = fmaf(W_s[k * kSS + i], sb[i * kS + s], acc);
    shT[(size_t)b * kS * kH + idx] = acc;
  }
}

__global__ void prep_base(const float* __restrict__ ww1, const float* __restrict__ ww2,
                          float* __restrict__ ws) {
  const int b = blockIdx.x, which = blockIdx.y, tid = threadIdx.x;
  const float* sh_g = ws + OFF_SHG + (size_t)b * kH * kS;
  const float* dh_g = ws + OFF_DHG + (size_t)b * kH * kS;
  const float* ww = which ? ww2 : ww1;
  const int dh_off = which ? 2 * kH : kH;
  float* dst = ws + (which ? OFF_BASE2 : OFF_BASE1) + (size_t)b * kH * kS;
  for (int idx = tid; idx < kH * kS / 4; idx += 256) {
    int h = idx >> 5, sq = idx & 31;
    const float* wrow = ww + h * kG3;
    float4 acc = make_float4(0.f, 0.f, 0.f, 0.f);
#pragma unroll 8
    for (int k = 0; k < kH; ++k) {
      float w = wrow[k];
      float4 v = *reinterpret_cast<const float4*>(sh_g + k * kS + sq * 4);
      acc.x = fmaf(w, v.x, acc.x); acc.y = fmaf(w, v.y, acc.y);
      acc.z = fmaf(w, v.z, acc.z); acc.w = fmaf(w, v.w, acc.w);
    }
#pragma unroll 8
    for (int k = 0; k < kH; ++k) {
      float w = wrow[dh_off + k];
      float4 v = *reinterpret_cast<const float4*>(dh_g + k * kS + sq * 4);
      acc.x = fmaf(w, v.x, acc.x); acc.y = fmaf(w, v.y, acc.y);
      acc.z = fmaf(w, v.z, acc.z); acc.w = fmaf(w, v.w, acc.w);
    }
    *reinterpret_cast<float4*>(dst + h * kS + sq * 4) = acc;
  }
}

// ---------------- main sequential kernel ----------------

__global__ __launch_bounds__(512)
__attribute__((amdgpu_waves_per_eu(2)))
void ptrnet_main(
    const float* __restrict__ stat_g, const float* __restrict__ dyn_g,
    const float* __restrict__ vv1_g, const float* __restrict__ vv2_g,
    const float* __restrict__ bhh_g, const float* __restrict__ Whh_g,
    const float* __restrict__ ws, float* __restrict__ out) {
  extern __shared__ float sm[];
  const int b = blockIdx.x;
  const int tid = threadIdx.x;
  const int hh = tid & 127;          // output/s index
  const int seg = tid >> 7;          // 0..3: 32-wide k/h chunk
  const int lane = tid & 63;
  const int li = seg * 32 + (hh & 31);  // this thread's "owned" 128-index

  float* base1_l = sm + L_BASE1;
  float* base2_l = sm + L_BASE2;
  float* wct_l   = sm + L_WCT;
  float* bc_l    = sm + L_BC;
  float* bh_l    = sm + L_BH;
  float* stat_l  = sm + L_STAT;
  float* pg_l    = sm + L_PG;
  float* pu_l    = sm + L_PU;
  float* pa_l    = sm + L_PA;
  float* mask_l  = sm + L_MASK;
  float* dec_l   = sm + L_DEC;
  float* wsum_l  = sm + L_WSUM;
  float* rinv_l  = sm + L_RINV;

  // ---- LDS init (one-time) ----
  {
    const float4* b1g = reinterpret_cast<const float4*>(ws + OFF_BASE1 + (size_t)b * kH * kS);
    const float4* b2g = reinterpret_cast<const float4*>(ws + OFF_BASE2 + (size_t)b * kH * kS);
    float4* b1l = reinterpret_cast<float4*>(base1_l);
    float4* b2l = reinterpret_cast<float4*>(base2_l);
    for (int i = tid; i < kH * kS / 4; i += 512) { b1l[i] = b1g[i]; b2l[i] = b2g[i]; }
    for (int i = tid; i < kSS * kG3; i += 512) wct_l[i] = ws[OFF_WCT + i];
    if (tid < kG3) { bc_l[tid] = ws[OFF_BCOMB + tid]; bh_l[tid] = bhh_g[tid]; }
    for (int i = tid; i < kSS * kS; i += 512) stat_l[i] = stat_g[(size_t)b * kSS * kS + i];
    if (tid < kS)
      mask_l[tid] = (tid == 0 || dyn_g[(size_t)b * kDS * kS + tid] != 0.f) ? 0.f : 1.f;
    if (tid < kSS) dec_l[tid] = 0.f;
  }

  // ---- persistent register caches (~230 VGPRs incl. working set) ----
  float w1r[32], w2r[32], shr[32];
  {
    const float* w1hT = ws + OFF_W1HT;
    const float* w2dT = ws + OFF_W2DT;
    const float* shT  = ws + OFF_SHT + (size_t)b * kS * kH;
#pragma unroll
    for (int kk = 0; kk < 32; ++kk) {
      int row = seg * 32 + kk;
      w1r[kk] = w1hT[row * kH + hh];
      w2r[kk] = w2dT[row * kH + hh];
      shr[kk] = shT[row * kH + hh];
    }
  }
  float whr0[32], whr1[32], whr2[32];
#pragma unroll
  for (int q = 0; q < 8; ++q) {
    float4 a0 = *reinterpret_cast<const float4*>(Whh_g + (0 * kH + hh) * kH + seg * 32 + q * 4);
    float4 a1 = *reinterpret_cast<const float4*>(Whh_g + (1 * kH + hh) * kH + seg * 32 + q * 4);
    float4 a2 = *reinterpret_cast<const float4*>(Whh_g + (2 * kH + hh) * kH + seg * 32 + q * 4);
    whr0[q*4+0]=a0.x; whr0[q*4+1]=a0.y; whr0[q*4+2]=a0.z; whr0[q*4+3]=a0.w;
    whr1[q*4+0]=a1.x; whr1[q*4+1]=a1.y; whr1[q*4+2]=a1.z; whr1[q*4+3]=a1.w;
    whr2[q*4+0]=a2.x; whr2[q*4+1]=a2.y; whr2[q*4+2]=a2.z; whr2[q*4+3]=a2.w;
  }
  float v_vv1 = vv1_g[li], v_vv2 = vv2_g[li];
  float h_prev = 0.f;
  __syncthreads();

  for (int t = 0; t < kT; ++t) {
    // ---- PH_A: gi (own li, kept in regs) + gh partials ----
    float gi0, gi1, gi2;
    {
      float v_dec = dec_l[lane & 7];
      gi0 = bc_l[li]; gi1 = bc_l[kH + li]; gi2 = bc_l[2 * kH + li];
#pragma unroll
      for (int i = 0; i < 8; ++i) {
        float d = rlane(v_dec, i);
        gi0 = fmaf(wct_l[i * kG3 + li], d, gi0);
        gi1 = fmaf(wct_l[i * kG3 + kH + li], d, gi1);
        gi2 = fmaf(wct_l[i * kG3 + 2 * kH + li], d, gi2);
      }
      float a0 = 0.f, a1 = 0.f, a2 = 0.f;
#pragma unroll
      for (int kk = 0; kk < 32; ++kk) {
        float hv = rlane(h_prev, kk);
        a0 = fmaf(whr0[kk], hv, a0);
        a1 = fmaf(whr1[kk], hv, a1);
        a2 = fmaf(whr2[kk], hv, a2);
      }
      pg_l[(seg * 3 + 0) * kS + hh] = a0;
      pg_l[(seg * 3 + 1) * kS + hh] = a1;
      pg_l[(seg * 3 + 2) * kS + hh] = a2;
    }
    __syncthreads();

    // ---- PH_B: GRU (replicated per-thread for own li) + u1 partials ----
    {
      float gh0 = bh_l[li] +
          ((pg_l[(0*3+0)*kS+li] + pg_l[(1*3+0)*kS+li]) + (pg_l[(2*3+0)*kS+li] + pg_l[(3*3+0)*kS+li]));
      float gh1 = bh_l[kH + li] +
          ((pg_l[(0*3+1)*kS+li] + pg_l[(1*3+1)*kS+li]) + (pg_l[(2*3+1)*kS+li] + pg_l[(3*3+1)*kS+li]));
      float gh2 = bh_l[2*kH + li] +
          ((pg_l[(0*3+2)*kS+li] + pg_l[(1*3+2)*kS+li]) + (pg_l[(2*3+2)*kS+li] + pg_l[(3*3+2)*kS+li]));
      float r = 1.f / (1.f + __expf(-(gi0 + gh0)));
      float z = 1.f / (1.f + __expf(-(gi1 + gh1)));
      float x = gi2 + r * gh2;
      x = fminf(15.f, fmaxf(-15.f, x));
      float e = __expf(-2.f * x);
      float n = (1.f - e) / (1.f + e);
      float hnew = (1.f - z) * n + z * h_prev;
      h_prev = hnew;
      float acc0 = 0.f, acc1 = 0.f;
#pragma unroll
      for (int kk = 0; kk < 16; ++kk) {
        acc0 = fmaf(rlane(hnew, 2 * kk), w1r[2 * kk], acc0);
        acc1 = fmaf(rlane(hnew, 2 * kk + 1), w1r[2 * kk + 1], acc1);
      }
      pu_l[seg * kS + hh] = acc0 + acc1;
    }
    __syncthreads();

    // ---- PH_C: attn1 partials (tanh over 32 h-rows) ----
    {
      float v_u1 = (pu_l[li] + pu_l[kS + li]) + (pu_l[2*kS + li] + pu_l[3*kS + li]);
      float acc0 = 0.f, acc1 = 0.f;
#pragma unroll
      for (int kk = 0; kk < 16; ++kk) {
        float xa = base1_l[(seg * 32 + 2*kk) * kS + hh] + rlane(v_u1, 2*kk);
        float xb = base1_l[(seg * 32 + 2*kk+1) * kS + hh] + rlane(v_u1, 2*kk+1);
        acc0 = fmaf(rlane(v_vv1, 2*kk), tanh_fast(xa), acc0);
        acc1 = fmaf(rlane(v_vv1, 2*kk+1), tanh_fast(xb), acc1);
      }
      pa_l[seg * kS + hh] = acc0 + acc1;
    }
    __syncthreads();

    // ---- PH_E: softmax1 exp (no max-sub) + chunk sums + dytext partials ----
    {
      float a = (pa_l[li] + pa_l[kS + li]) + (pa_l[2*kS + li] + pa_l[3*kS + li]);
      float ee = __expf(fminf(a, 60.f));
      float ssum = ee;
#pragma unroll
      for (int off = 1; off < 32; off <<= 1) ssum += __shfl_xor(ssum, off);
      if ((lane & 31) == 0) wsum_l[seg] = ssum;
      float acc0 = 0.f, acc1 = 0.f;
#pragma unroll
      for (int kk = 0; kk < 16; ++kk) {
        acc0 = fmaf(rlane(ee, 2 * kk), shr[2 * kk], acc0);
        acc1 = fmaf(rlane(ee, 2 * kk + 1), shr[2 * kk + 1], acc1);
      }
      pu_l[seg * kS + hh] = acc0 + acc1;
    }
    __syncthreads();

    // ---- PH_F: u2 partials; one thread computes 1/sum ----
    {
      float v_dy = (pu_l[li] + pu_l[kS + li]) + (pu_l[2*kS + li] + pu_l[3*kS + li]);
      float acc0 = 0.f, acc1 = 0.f;
#pragma unroll
      for (int kk = 0; kk < 16; ++kk) {
        acc0 = fmaf(rlane(v_dy, 2 * kk), w2r[2 * kk], acc0);
        acc1 = fmaf(rlane(v_dy, 2 * kk + 1), w2r[2 * kk + 1], acc1);
      }
      pa_l[seg * kS + hh] = acc0 + acc1;
      if (tid == 0) rinv_l[0] = 1.0f / ((wsum_l[0] + wsum_l[1]) + (wsum_l[2] + wsum_l[3]));
    }
    __syncthreads();

    // ---- PH_G: attn2 partials (tanh over 32 h-rows) ----
    {
      float rin = rinv_l[0];
      float v_u2 = ((pa_l[li] + pa_l[kS + li]) + (pa_l[2*kS + li] + pa_l[3*kS + li])) * rin;
      float acc0 = 0.f, acc1 = 0.f;
#pragma unroll
      for (int kk = 0; kk < 16; ++kk) {
        float xa = base2_l[(seg * 32 + 2*kk) * kS + hh] + rlane(v_u2, 2*kk);
        float xb = base2_l[(seg * 32 + 2*kk+1) * kS + hh] + rlane(v_u2, 2*kk+1);
        acc0 = fmaf(rlane(v_vv2, 2*kk), tanh_fast(xa), acc0);
        acc1 = fmaf(rlane(v_vv2, 2*kk+1), tanh_fast(xb), acc1);
      }
      pu_l[seg * kS + hh] = acc0 + acc1;
    }
    __syncthreads();

    // ---- PH_H: logits, argmax, logsumexp, state update (wave 0 only) ----
    if (tid < 64) {
      int s0 = lane, s1 = lane + 64;
      float l0 = (pu_l[s0] + pu_l[kS + s0]) + (pu_l[2*kS + s0] + pu_l[3*kS + s0]);
      float l1 = (pu_l[s1] + pu_l[kS + s1]) + (pu_l[2*kS + s1] + pu_l[3*kS + s1]);
      l0 += (mask_l[s0] > 0.f ? 0.f : -1e30f);
      l1 += (mask_l[s1] > 0.f ? 0.f : -1e30f);
      float es = __expf(l0) + __expf(l1);
      float mv; int mi;
      if (l1 > l0) { mv = l1; mi = s1; } else { mv = l0; mi = s0; }
#pragma unroll
      for (int off = 1; off < 64; off <<= 1) {
        float ov = __shfl_xor(mv, off);
        int oi = __shfl_xor(mi, off);
        if (ov > mv || (ov == mv && oi < mi)) { mv = ov; mi = oi; }
        es += __shfl_xor(es, off);
      }
      if (lane == 0) {
        out[b * kT + t] = (float)mi;
        out[kB * kT + b * kT + t] = mv - __logf(es);
        mask_l[mi] = 0.f;
      }
      if (lane < kSS) dec_l[lane] = stat_l[lane * kS + mi];
    }
    __syncthreads();
  }
}

}  // namespace

extern "C" void kernel_launch(void* const* d_in, const int* in_sizes, int n_in,
                              void* d_out, int out_size, void* d_ws, size_t ws_size,
                              hipStream_t stream) {
  const float* stat_g = (const float*)d_in[0];
  const float* dyn_g  = (const float*)d_in[1];
  const float* W_s   = (const float*)d_in[3];
  const float* b_s   = (const float*)d_in[4];
  const float* W_d   = (const float*)d_in[5];
  const float* b_d   = (const float*)d_in[6];
  const float* W_dec = (const float*)d_in[7];
  const float* b_dec = (const float*)d_in[8];
  const float* vv1   = (const float*)d_in[9];
  const float* ww1   = (const float*)d_in[10];
  const float* vv2   = (const float*)d_in[11];
  const float* ww2   = (const float*)d_in[12];
  const float* W_ih  = (const float*)d_in[13];
  const float* W_hh  = (const float*)d_in[14];
  const float* b_ih  = (const float*)d_in[15];
  const float* b_hh  = (const float*)d_in[16];

  float* ws = (float*)d_ws;
  float* out = (float*)d_out;

  hipFuncSetAttribute(reinterpret_cast<const void*>(ptrnet_main),
                      hipFuncAttributeMaxDynamicSharedMemorySize, LDS_BYTES);

  prep_w<<<1, 256, 0, stream>>>(W_ih, W_dec, b_ih, b_dec, ww1, ww2, ws);
  prep_sh<<<kB, 256, 0, stream>>>(stat_g, dyn_g, W_s, b_s, W_d, b_d, ws);
  prep_base<<<dim3(kB, 2), 256, 0, stream>>>(ww1, ww2, ws);
  ptrnet_main<<<kB, 512, LDS_BYTES, stream>>>(stat_g, dyn_g, vv1, vv2, b_hh, W_hh, ws, out);
}

// Round 8
// 1473.043 us; speedup vs baseline: 1.1528x; 1.1511x over previous
//
#include <hip/hip_runtime.h>

// DRL4SSP pointer-network decoder, MI355X (gfx950).
// 64 batches -> 64 blocks x 512 threads, 127 sequential steps, 7 barriers/step.
// base1/base2/Wcomb/static in LDS (161 KB). Whh fragments (96 floats) in
// registers; w1h/w2d/static_h STREAMED from L2 per step with double-buffered
// coalesced chunks, keeping peak register pressure ~128 so nothing spills
// regardless of the allocator's occupancy target.

namespace {

constexpr int kB = 64, kSS = 8, kDS = 4, kH = 128, kS = 128, kT = 127, kG3 = 384;

// workspace layout (float offsets)
constexpr size_t OFF_BASE1 = 0;
constexpr size_t OFF_BASE2 = OFF_BASE1 + (size_t)kB * kH * kS;
constexpr size_t OFF_SHG   = OFF_BASE2 + (size_t)kB * kH * kS;
constexpr size_t OFF_DHG   = OFF_SHG   + (size_t)kB * kH * kS;
constexpr size_t OFF_SHT   = OFF_DHG   + (size_t)kB * kH * kS;
constexpr size_t OFF_WCT   = OFF_SHT   + (size_t)kB * kS * kH;  // WcombT [8][384]
constexpr size_t OFF_BCOMB = OFF_WCT   + (size_t)kSS * kG3;
constexpr size_t OFF_W1HT  = OFF_BCOMB + (size_t)kG3;
constexpr size_t OFF_W2DT  = OFF_W1HT  + (size_t)kH * kH;
// total = OFF_W2DT + kH*kH = 5,279,104 floats (~21.1 MB)

// dynamic-LDS layout (float offsets)
constexpr int L_BASE1 = 0;        // 16384
constexpr int L_BASE2 = 16384;    // 16384
constexpr int L_WCT   = 32768;    // 3072
constexpr int L_BC    = 35840;    // 384
constexpr int L_BH    = 36224;    // 384
constexpr int L_STAT  = 36608;    // 1024
constexpr int L_PG    = 37632;    // 1536  [seg][gate][128]
constexpr int L_PU    = 39168;    // 512
constexpr int L_PA    = 39680;    // 512
constexpr int L_MASK  = 40192;    // 128
constexpr int L_DEC   = 40320;    // 8
constexpr int L_WSUM  = 40328;    // 4
constexpr int L_RINV  = 40332;    // 1
constexpr int LDS_FLOATS = 40336;
constexpr int LDS_BYTES  = LDS_FLOATS * 4;  // 161,344 <= 163,840

__device__ __forceinline__ float rlane(float v, int l) {
  return __uint_as_float(__builtin_amdgcn_readlane(__float_as_uint(v), (unsigned)l));
}

__device__ __forceinline__ float tanh_fast(float x) {
  // identical to the round-1/2/4/5 (passing) formula — trajectory-sensitive
  x = fminf(15.f, fmaxf(-15.f, x));
  float e = __expf(-2.f * x);
  return (1.f - e) * __builtin_amdgcn_rcpf(1.f + e);
}

// ---------------- precompute kernels ----------------

__global__ void prep_w(const float* __restrict__ W_ih, const float* __restrict__ W_dec,
                       const float* __restrict__ b_ih, const float* __restrict__ b_dec,
                       const float* __restrict__ ww1, const float* __restrict__ ww2,
                       float* __restrict__ ws) {
  const int tid = threadIdx.x;
  float* WcT  = ws + OFF_WCT;    // [i][j] = sum_k W_ih[j,k] W_dec[k,i]
  float* bcomb = ws + OFF_BCOMB;
  float* w1hT  = ws + OFF_W1HT;
  float* w2dT  = ws + OFF_W2DT;
  for (int idx = tid; idx < kSS * kG3; idx += 256) {
    int i = idx / kG3, j = idx % kG3;
    float acc = 0.f;
    for (int k = 0; k < kH; ++k) acc = fmaf(W_ih[j * kH + k], W_dec[k * kSS + i], acc);
    WcT[idx] = acc;
  }
  for (int j = tid; j < kG3; j += 256) {
    float acc = b_ih[j];
    for (int k = 0; k < kH; ++k) acc = fmaf(W_ih[j * kH + k], b_dec[k], acc);
    bcomb[j] = acc;
  }
  for (int idx = tid; idx < kH * kH; idx += 256) {
    int k = idx >> 7, h = idx & 127;
    w1hT[idx] = ww1[h * kG3 + 2 * kH + k];  // w1h = ww1[:, 2H:3H]
    w2dT[idx] = ww2[h * kG3 + kH + k];      // w2d = ww2[:, H:2H]
  }
}

__global__ void prep_sh(const float* __restrict__ stat_g, const float* __restrict__ dyn_g,
                        const float* __restrict__ W_s, const float* __restrict__ b_s,
                        const float* __restrict__ W_d, const float* __restrict__ b_d,
                        float* __restrict__ ws) {
  const int b = blockIdx.x, tid = threadIdx.x;
  float* sh_g = ws + OFF_SHG;
  float* dh_g = ws + OFF_DHG;
  float* shT  = ws + OFF_SHT;
  const float* sb = stat_g + (size_t)b * kSS * kS;
  const float* db = dyn_g + (size_t)b * kDS * kS;
  for (int idx = tid; idx < kH * kS; idx += 256) {
    int k = idx >> 7, s = idx & 127;
    float acc = b_s[k];
#pragma unroll
    for (int i = 0; i < kSS; ++i) acc = fmaf(W_s[k * kSS + i], sb[i * kS + s], acc);
    sh_g[(size_t)b * kH * kS + idx] = acc;
    float accd = b_d[k];
#pragma unroll
    for (int i = 0; i < kDS; ++i) accd = fmaf(W_d[k * kDS + i], db[i * kS + s], accd);
    dh_g[(size_t)b * kH * kS + idx] = accd;
  }
  for (int idx = tid; idx < kS * kH; idx += 256) {
    int s = idx >> 7, k = idx & 127;
    float acc = b_s[k];
#pragma unroll
    for (int i = 0; i < kSS; ++i) acc = fmaf(W_s[k * kSS + i], sb[i * kS + s], acc);
    shT[(size_t)b * kS * kH + idx] = acc;
  }
}

__global__ void prep_base(const float* __restrict__ ww1, const float* __restrict__ ww2,
                          float* __restrict__ ws) {
  const int b = blockIdx.x, which = blockIdx.y, tid = threadIdx.x;
  const float* sh_g = ws + OFF_SHG + (size_t)b * kH * kS;
  const float* dh_g = ws + OFF_DHG + (size_t)b * kH * kS;
  const float* ww = which ? ww2 : ww1;
  const int dh_off = which ? 2 * kH : kH;
  float* dst = ws + (which ? OFF_BASE2 : OFF_BASE1) + (size_t)b * kH * kS;
  for (int idx = tid; idx < kH * kS / 4; idx += 256) {
    int h = idx >> 5, sq = idx & 31;
    const float* wrow = ww + h * kG3;
    float4 acc = make_float4(0.f, 0.f, 0.f, 0.f);
#pragma unroll 8
    for (int k = 0; k < kH; ++k) {
      float w = wrow[k];
      float4 v = *reinterpret_cast<const float4*>(sh_g + k * kS + sq * 4);
      acc.x = fmaf(w, v.x, acc.x); acc.y = fmaf(w, v.y, acc.y);
      acc.z = fmaf(w, v.z, acc.z); acc.w = fmaf(w, v.w, acc.w);
    }
#pragma unroll 8
    for (int k = 0; k < kH; ++k) {
      float w = wrow[dh_off + k];
      float4 v = *reinterpret_cast<const float4*>(dh_g + k * kS + sq * 4);
      acc.x = fmaf(w, v.x, acc.x); acc.y = fmaf(w, v.y, acc.y);
      acc.z = fmaf(w, v.z, acc.z); acc.w = fmaf(w, v.w, acc.w);
    }
    *reinterpret_cast<float4*>(dst + h * kS + sq * 4) = acc;
  }
}

// ---------------- main sequential kernel ----------------

__global__ __launch_bounds__(512)
__attribute__((amdgpu_waves_per_eu(2, 2)))
void ptrnet_main(
    const float* __restrict__ stat_g, const float* __restrict__ dyn_g,
    const float* __restrict__ vv1_g, const float* __restrict__ vv2_g,
    const float* __restrict__ bhh_g, const float* __restrict__ Whh_g,
    const float* __restrict__ ws, float* __restrict__ out) {
  extern __shared__ float sm[];
  const int b = blockIdx.x;
  const int tid = threadIdx.x;
  const int hh = tid & 127;          // output/s index
  const int seg = tid >> 7;          // 0..3: 32-wide k/h chunk
  const int lane = tid & 63;
  const int li = seg * 32 + (hh & 31);  // this thread's "owned" 128-index

  float* base1_l = sm + L_BASE1;
  float* base2_l = sm + L_BASE2;
  float* wct_l   = sm + L_WCT;
  float* bc_l    = sm + L_BC;
  float* bh_l    = sm + L_BH;
  float* stat_l  = sm + L_STAT;
  float* pg_l    = sm + L_PG;
  float* pu_l    = sm + L_PU;
  float* pa_l    = sm + L_PA;
  float* mask_l  = sm + L_MASK;
  float* dec_l   = sm + L_DEC;
  float* wsum_l  = sm + L_WSUM;
  float* rinv_l  = sm + L_RINV;

  // ---- LDS init (one-time) ----
  {
    const float4* b1g = reinterpret_cast<const float4*>(ws + OFF_BASE1 + (size_t)b * kH * kS);
    const float4* b2g = reinterpret_cast<const float4*>(ws + OFF_BASE2 + (size_t)b * kH * kS);
    float4* b1l = reinterpret_cast<float4*>(base1_l);
    float4* b2l = reinterpret_cast<float4*>(base2_l);
    for (int i = tid; i < kH * kS / 4; i += 512) { b1l[i] = b1g[i]; b2l[i] = b2g[i]; }
    for (int i = tid; i < kSS * kG3; i += 512) wct_l[i] = ws[OFF_WCT + i];
    if (tid < kG3) { bc_l[tid] = ws[OFF_BCOMB + tid]; bh_l[tid] = bhh_g[tid]; }
    for (int i = tid; i < kSS * kS; i += 512) stat_l[i] = stat_g[(size_t)b * kSS * kS + i];
    if (tid < kS)
      mask_l[tid] = (tid == 0 || dyn_g[(size_t)b * kDS * kS + tid] != 0.f) ? 0.f : 1.f;
    if (tid < kSS) dec_l[tid] = 0.f;
  }

  // ---- persistent register cache: Whh fragments only (96 VGPRs) ----
  float whr0[32], whr1[32], whr2[32];
#pragma unroll
  for (int q = 0; q < 8; ++q) {
    float4 a0 = *reinterpret_cast<const float4*>(Whh_g + (0 * kH + hh) * kH + seg * 32 + q * 4);
    float4 a1 = *reinterpret_cast<const float4*>(Whh_g + (1 * kH + hh) * kH + seg * 32 + q * 4);
    float4 a2 = *reinterpret_cast<const float4*>(Whh_g + (2 * kH + hh) * kH + seg * 32 + q * 4);
    whr0[q*4+0]=a0.x; whr0[q*4+1]=a0.y; whr0[q*4+2]=a0.z; whr0[q*4+3]=a0.w;
    whr1[q*4+0]=a1.x; whr1[q*4+1]=a1.y; whr1[q*4+2]=a1.z; whr1[q*4+3]=a1.w;
    whr2[q*4+0]=a2.x; whr2[q*4+1]=a2.y; whr2[q*4+2]=a2.z; whr2[q*4+3]=a2.w;
  }
  float v_vv1 = vv1_g[li], v_vv2 = vv2_g[li];
  float h_prev = 0.f;

  // streamed weight base pointers (column hh, rows seg*32..seg*32+31)
  const float* w1p = ws + OFF_W1HT + (size_t)(seg * 32) * kH + hh;
  const float* w2p = ws + OFF_W2DT + (size_t)(seg * 32) * kH + hh;
  const float* shp = ws + OFF_SHT + (size_t)b * kS * kH + (size_t)(seg * 32) * kH + hh;
  __syncthreads();

  for (int t = 0; t < kT; ++t) {
    // ---- PH_A: gi (own li, kept in regs) + gh partials ----
    float gi0, gi1, gi2;
    {
      float v_dec = dec_l[lane & 7];
      gi0 = bc_l[li]; gi1 = bc_l[kH + li]; gi2 = bc_l[2 * kH + li];
#pragma unroll
      for (int i = 0; i < 8; ++i) {
        float d = rlane(v_dec, i);
        gi0 = fmaf(wct_l[i * kG3 + li], d, gi0);
        gi1 = fmaf(wct_l[i * kG3 + kH + li], d, gi1);
        gi2 = fmaf(wct_l[i * kG3 + 2 * kH + li], d, gi2);
      }
      float a0 = 0.f, a1 = 0.f, a2 = 0.f;
#pragma unroll
      for (int kk = 0; kk < 32; ++kk) {
        float hv = rlane(h_prev, kk);
        a0 = fmaf(whr0[kk], hv, a0);
        a1 = fmaf(whr1[kk], hv, a1);
        a2 = fmaf(whr2[kk], hv, a2);
      }
      pg_l[(seg * 3 + 0) * kS + hh] = a0;
      pg_l[(seg * 3 + 1) * kS + hh] = a1;
      pg_l[(seg * 3 + 2) * kS + hh] = a2;
    }
    __syncthreads();

    // ---- PH_B: GRU (replicated per-thread) + u1 partials (w1h streamed) ----
    {
      float b0[8], b1[8];
#pragma unroll
      for (int j = 0; j < 8; ++j) b0[j] = w1p[j * kH];
#pragma unroll
      for (int j = 0; j < 8; ++j) b1[j] = w1p[(8 + j) * kH];
      float gh0 = bh_l[li] +
          ((pg_l[(0*3+0)*kS+li] + pg_l[(1*3+0)*kS+li]) + (pg_l[(2*3+0)*kS+li] + pg_l[(3*3+0)*kS+li]));
      float gh1 = bh_l[kH + li] +
          ((pg_l[(0*3+1)*kS+li] + pg_l[(1*3+1)*kS+li]) + (pg_l[(2*3+1)*kS+li] + pg_l[(3*3+1)*kS+li]));
      float gh2 = bh_l[2*kH + li] +
          ((pg_l[(0*3+2)*kS+li] + pg_l[(1*3+2)*kS+li]) + (pg_l[(2*3+2)*kS+li] + pg_l[(3*3+2)*kS+li]));
      float r = 1.f / (1.f + __expf(-(gi0 + gh0)));
      float z = 1.f / (1.f + __expf(-(gi1 + gh1)));
      float x = gi2 + r * gh2;
      x = fminf(15.f, fmaxf(-15.f, x));
      float e = __expf(-2.f * x);
      float n = (1.f - e) / (1.f + e);
      float hnew = (1.f - z) * n + z * h_prev;
      h_prev = hnew;
      float acc0 = 0.f, acc1 = 0.f;
#pragma unroll
      for (int j = 0; j < 8; ++j) acc0 = fmaf(rlane(hnew, j), b0[j], acc0);
#pragma unroll
      for (int j = 0; j < 8; ++j) b0[j] = w1p[(16 + j) * kH];
#pragma unroll
      for (int j = 0; j < 8; ++j) acc1 = fmaf(rlane(hnew, 8 + j), b1[j], acc1);
#pragma unroll
      for (int j = 0; j < 8; ++j) b1[j] = w1p[(24 + j) * kH];
#pragma unroll
      for (int j = 0; j < 8; ++j) acc0 = fmaf(rlane(hnew, 16 + j), b0[j], acc0);
#pragma unroll
      for (int j = 0; j < 8; ++j) acc1 = fmaf(rlane(hnew, 24 + j), b1[j], acc1);
      pu_l[seg * kS + hh] = acc0 + acc1;
    }
    __syncthreads();

    // ---- PH_C: attn1 partials (tanh over 32 h-rows, base1 in LDS) ----
    {
      float v_u1 = (pu_l[li] + pu_l[kS + li]) + (pu_l[2*kS + li] + pu_l[3*kS + li]);
      float acc0 = 0.f, acc1 = 0.f;
#pragma unroll
      for (int kk = 0; kk < 16; ++kk) {
        float xa = base1_l[(seg * 32 + 2*kk) * kS + hh] + rlane(v_u1, 2*kk);
        float xb = base1_l[(seg * 32 + 2*kk+1) * kS + hh] + rlane(v_u1, 2*kk+1);
        acc0 = fmaf(rlane(v_vv1, 2*kk), tanh_fast(xa), acc0);
        acc1 = fmaf(rlane(v_vv1, 2*kk+1), tanh_fast(xb), acc1);
      }
      pa_l[seg * kS + hh] = acc0 + acc1;
    }
    __syncthreads();

    // ---- PH_E: softmax1 exp + chunk sums + dytext partials (static_h streamed) ----
    {
      float b0[8], b1[8];
#pragma unroll
      for (int j = 0; j < 8; ++j) b0[j] = shp[j * kH];
#pragma unroll
      for (int j = 0; j < 8; ++j) b1[j] = shp[(8 + j) * kH];
      float a = (pa_l[li] + pa_l[kS + li]) + (pa_l[2*kS + li] + pa_l[3*kS + li]);
      float ee = __expf(fminf(a, 60.f));
      float ssum = ee;
#pragma unroll
      for (int off = 1; off < 32; off <<= 1) ssum += __shfl_xor(ssum, off);
      if ((lane & 31) == 0) wsum_l[seg] = ssum;
      float acc0 = 0.f, acc1 = 0.f;
#pragma unroll
      for (int j = 0; j < 8; ++j) acc0 = fmaf(rlane(ee, j), b0[j], acc0);
#pragma unroll
      for (int j = 0; j < 8; ++j) b0[j] = shp[(16 + j) * kH];
#pragma unroll
      for (int j = 0; j < 8; ++j) acc1 = fmaf(rlane(ee, 8 + j), b1[j], acc1);
#pragma unroll
      for (int j = 0; j < 8; ++j) b1[j] = shp[(24 + j) * kH];
#pragma unroll
      for (int j = 0; j < 8; ++j) acc0 = fmaf(rlane(ee, 16 + j), b0[j], acc0);
#pragma unroll
      for (int j = 0; j < 8; ++j) acc1 = fmaf(rlane(ee, 24 + j), b1[j], acc1);
      pu_l[seg * kS + hh] = acc0 + acc1;
    }
    __syncthreads();

    // ---- PH_F: u2 partials (w2d streamed); one thread computes 1/sum ----
    {
      float b0[8], b1[8];
#pragma unroll
      for (int j = 0; j < 8; ++j) b0[j] = w2p[j * kH];
#pragma unroll
      for (int j = 0; j < 8; ++j) b1[j] = w2p[(8 + j) * kH];
      float v_dy = (pu_l[li] + pu_l[kS + li]) + (pu_l[2*kS + li] + pu_l[3*kS + li]);
      float acc0 = 0.f, acc1 = 0.f;
#pragma unroll
      for (int j = 0; j < 8; ++j) acc0 = fmaf(rlane(v_dy, j), b0[j], acc0);
#pragma unroll
      for (int j = 0; j < 8; ++j) b0[j] = w2p[(16 + j) * kH];
#pragma unroll
      for (int j = 0; j < 8; ++j) acc1 = fmaf(rlane(v_dy, 8 + j), b1[j], acc1);
#pragma unroll
      for (int j = 0; j < 8; ++j) b1[j] = w2p[(24 + j) * kH];
#pragma unroll
      for (int j = 0; j < 8; ++j) acc0 = fmaf(rlane(v_dy, 16 + j), b0[j], acc0);
#pragma unroll
      for (int j = 0; j < 8; ++j) acc1 = fmaf(rlane(v_dy, 24 + j), b1[j], acc1);
      pa_l[seg * kS + hh] = acc0 + acc1;
      if (tid == 0) rinv_l[0] = 1.0f / ((wsum_l[0] + wsum_l[1]) + (wsum_l[2] + wsum_l[3]));
    }
    __syncthreads();

    // ---- PH_G: attn2 partials (tanh over 32 h-rows, base2 in LDS) ----
    {
      float rin = rinv_l[0];
      float v_u2 = ((pa_l[li] + pa_l[kS + li]) + (pa_l[2*kS + li] + pa_l[3*kS + li])) * rin;
      float acc0 = 0.f, acc1 = 0.f;
#pragma unroll
      for (int kk = 0; kk < 16; ++kk) {
        float xa = base2_l[(seg * 32 + 2*kk) * kS + hh] + rlane(v_u2, 2*kk);
        float xb = base2_l[(seg * 32 + 2*kk+1) * kS + hh] + rlane(v_u2, 2*kk+1);
        acc0 = fmaf(rlane(v_vv2, 2*kk), tanh_fast(xa), acc0);
        acc1 = fmaf(rlane(v_vv2, 2*kk+1), tanh_fast(xb), acc1);
      }
      pu_l[seg * kS + hh] = acc0 + acc1;
    }
    __syncthreads();

    // ---- PH_H: logits, argmax, logsumexp, state update (wave 0 only) ----
    if (tid < 64) {
      int s0 = lane, s1 = lane + 64;
      float l0 = (pu_l[s0] + pu_l[kS + s0]) + (pu_l[2*kS + s0] + pu_l[3*kS + s0]);
      float l1 = (pu_l[s1] + pu_l[kS + s1]) + (pu_l[2*kS + s1] + pu_l[3*kS + s1]);
      l0 += (mask_l[s0] > 0.f ? 0.f : -1e30f);
      l1 += (mask_l[s1] > 0.f ? 0.f : -1e30f);
      float es = __expf(l0) + __expf(l1);
      float mv; int mi;
      if (l1 > l0) { mv = l1; mi = s1; } else { mv = l0; mi = s0; }
#pragma unroll
      for (int off = 1; off < 64; off <<= 1) {
        float ov = __shfl_xor(mv, off);
        int oi = __shfl_xor(mi, off);
        if (ov > mv || (ov == mv && oi < mi)) { mv = ov; mi = oi; }
        es += __shfl_xor(es, off);
      }
      if (lane == 0) {
        out[b * kT + t] = (float)mi;
        out[kB * kT + b * kT + t] = mv - __logf(es);
        mask_l[mi] = 0.f;
      }
      if (lane < kSS) dec_l[lane] = stat_l[lane * kS + mi];
    }
    __syncthreads();
  }
}

}  // namespace

extern "C" void kernel_launch(void* const* d_in, const int* in_sizes, int n_in,
                              void* d_out, int out_size, void* d_ws, size_t ws_size,
                              hipStream_t stream) {
  const float* stat_g = (const float*)d_in[0];
  const float* dyn_g  = (const float*)d_in[1];
  const float* W_s   = (const float*)d_in[3];
  const float* b_s   = (const float*)d_in[4];
  const float* W_d   = (const float*)d_in[5];
  const float* b_d   = (const float*)d_in[6];
  const float* W_dec = (const float*)d_in[7];
  const float* b_dec = (const float*)d_in[8];
  const float* vv1   = (const float*)d_in[9];
  const float* ww1   = (const float*)d_in[10];
  const float* vv2   = (const float*)d_in[11];
  const float* ww2   = (const float*)d_in[12];
  const float* W_ih  = (const float*)d_in[13];
  const float* W_hh  = (const float*)d_in[14];
  const float* b_ih  = (const float*)d_in[15];
  const float* b_hh  = (const float*)d_in[16];

  float* ws = (float*)d_ws;
  float* out = (float*)d_out;

  hipFuncSetAttribute(reinterpret_cast<const void*>(ptrnet_main),
                      hipFuncAttributeMaxDynamicSharedMemorySize, LDS_BYTES);

  prep_w<<<1, 256, 0, stream>>>(W_ih, W_dec, b_ih, b_dec, ww1, ww2, ws);
  prep_sh<<<kB, 256, 0, stream>>>(stat_g, dyn_g, W_s, b_s, W_d, b_d, ws);
  prep_base<<<dim3(kB, 2), 256, 0, stream>>>(ww1, ww2, ws);
  ptrnet_main<<<kB, 512, LDS_BYTES, stream>>>(stat_g, dyn_g, vv1, vv2, b_hh, W_hh, ws, out);
}

// Round 9
// 1407.948 us; speedup vs baseline: 1.2061x; 1.0462x over previous
//
#include <hip/hip_runtime.h>

// DRL4SSP pointer-network decoder, MI355X (gfx950).
// 64 batches -> 64 blocks x 512 threads, 127 sequential steps, 7 barriers/step.
// base1/base2/Wcomb/static in LDS (161 KB). ALL weight matrices (Whh, w1h,
// w2d, static_h^T) streamed from L2 per step with phase-local prefetch;
// persistent register state ~20 floats -> fits the 128-VGPR cap with ZERO
// scratch spill. Streamed loads issue at phase top so L2 latency hides under
// the phase's LDS reads + GRU/exp math.

namespace {

constexpr int kB = 64, kSS = 8, kDS = 4, kH = 128, kS = 128, kT = 127, kG3 = 384;

// workspace layout (float offsets)
constexpr size_t OFF_BASE1 = 0;
constexpr size_t OFF_BASE2 = OFF_BASE1 + (size_t)kB * kH * kS;
constexpr size_t OFF_SHG   = OFF_BASE2 + (size_t)kB * kH * kS;
constexpr size_t OFF_DHG   = OFF_SHG   + (size_t)kB * kH * kS;
constexpr size_t OFF_SHT   = OFF_DHG   + (size_t)kB * kH * kS;
constexpr size_t OFF_WCT   = OFF_SHT   + (size_t)kB * kS * kH;  // WcombT [8][384]
constexpr size_t OFF_BCOMB = OFF_WCT   + (size_t)kSS * kG3;
constexpr size_t OFF_W1HT  = OFF_BCOMB + (size_t)kG3;
constexpr size_t OFF_W2DT  = OFF_W1HT  + (size_t)kH * kH;
// total = OFF_W2DT + kH*kH = 5,279,104 floats (~21.1 MB)

// dynamic-LDS layout (float offsets)
constexpr int L_BASE1 = 0;        // 16384
constexpr int L_BASE2 = 16384;    // 16384
constexpr int L_WCT   = 32768;    // 3072
constexpr int L_BC    = 35840;    // 384
constexpr int L_BH    = 36224;    // 384
constexpr int L_STAT  = 36608;    // 1024
constexpr int L_PG    = 37632;    // 1536  [seg][gate][128]
constexpr int L_PU    = 39168;    // 512
constexpr int L_PA    = 39680;    // 512
constexpr int L_MASK  = 40192;    // 128
constexpr int L_DEC   = 40320;    // 8
constexpr int L_WSUM  = 40328;    // 4
constexpr int L_RINV  = 40332;    // 1
constexpr int LDS_FLOATS = 40336;
constexpr int LDS_BYTES  = LDS_FLOATS * 4;  // 161,344 <= 163,840

__device__ __forceinline__ float rlane(float v, int l) {
  return __uint_as_float(__builtin_amdgcn_readlane(__float_as_uint(v), (unsigned)l));
}

__device__ __forceinline__ float tanh_fast(float x) {
  // identical to the round-1/2/4/5/8 (passing) formula — trajectory-sensitive
  x = fminf(15.f, fmaxf(-15.f, x));
  float e = __expf(-2.f * x);
  return (1.f - e) * __builtin_amdgcn_rcpf(1.f + e);
}

// ---------------- precompute kernels ----------------

__global__ void prep_w(const float* __restrict__ W_ih, const float* __restrict__ W_dec,
                       const float* __restrict__ b_ih, const float* __restrict__ b_dec,
                       const float* __restrict__ ww1, const float* __restrict__ ww2,
                       float* __restrict__ ws) {
  const int tid = threadIdx.x;
  float* WcT  = ws + OFF_WCT;    // [i][j] = sum_k W_ih[j,k] W_dec[k,i]
  float* bcomb = ws + OFF_BCOMB;
  float* w1hT  = ws + OFF_W1HT;
  float* w2dT  = ws + OFF_W2DT;
  for (int idx = tid; idx < kSS * kG3; idx += 256) {
    int i = idx / kG3, j = idx % kG3;
    float acc = 0.f;
    for (int k = 0; k < kH; ++k) acc = fmaf(W_ih[j * kH + k], W_dec[k * kSS + i], acc);
    WcT[idx] = acc;
  }
  for (int j = tid; j < kG3; j += 256) {
    float acc = b_ih[j];
    for (int k = 0; k < kH; ++k) acc = fmaf(W_ih[j * kH + k], b_dec[k], acc);
    bcomb[j] = acc;
  }
  for (int idx = tid; idx < kH * kH; idx += 256) {
    int k = idx >> 7, h = idx & 127;
    w1hT[idx] = ww1[h * kG3 + 2 * kH + k];  // w1h = ww1[:, 2H:3H]
    w2dT[idx] = ww2[h * kG3 + kH + k];      // w2d = ww2[:, H:2H]
  }
}

__global__ void prep_sh(const float* __restrict__ stat_g, const float* __restrict__ dyn_g,
                        const float* __restrict__ W_s, const float* __restrict__ b_s,
                        const float* __restrict__ W_d, const float* __restrict__ b_d,
                        float* __restrict__ ws) {
  const int b = blockIdx.x, tid = threadIdx.x;
  float* sh_g = ws + OFF_SHG;
  float* dh_g = ws + OFF_DHG;
  float* shT  = ws + OFF_SHT;
  const float* sb = stat_g + (size_t)b * kSS * kS;
  const float* db = dyn_g + (size_t)b * kDS * kS;
  for (int idx = tid; idx < kH * kS; idx += 256) {
    int k = idx >> 7, s = idx & 127;
    float acc = b_s[k];
#pragma unroll
    for (int i = 0; i < kSS; ++i) acc = fmaf(W_s[k * kSS + i], sb[i * kS + s], acc);
    sh_g[(size_t)b * kH * kS + idx] = acc;
    float accd = b_d[k];
#pragma unroll
    for (int i = 0; i < kDS; ++i) accd = fmaf(W_d[k * kDS + i], db[i * kS + s], accd);
    dh_g[(size_t)b * kH * kS + idx] = accd;
  }
  for (int idx = tid; idx < kS * kH; idx += 256) {
    int s = idx >> 7, k = idx & 127;
    float acc = b_s[k];
#pragma unroll
    for (int i = 0; i < kSS; ++i) acc = fmaf(W_s[k * kSS + i], sb[i * kS + s], acc);
    shT[(size_t)b * kS * kH + idx] = acc;
  }
}

__global__ void prep_base(const float* __restrict__ ww1, const float* __restrict__ ww2,
                          float* __restrict__ ws) {
  const int b = blockIdx.x, which = blockIdx.y, tid = threadIdx.x;
  const float* sh_g = ws + OFF_SHG + (size_t)b * kH * kS;
  const float* dh_g = ws + OFF_DHG + (size_t)b * kH * kS;
  const float* ww = which ? ww2 : ww1;
  const int dh_off = which ? 2 * kH : kH;
  float* dst = ws + (which ? OFF_BASE2 : OFF_BASE1) + (size_t)b * kH * kS;
  for (int idx = tid; idx < kH * kS / 4; idx += 256) {
    int h = idx >> 5, sq = idx & 31;
    const float* wrow = ww + h * kG3;
    float4 acc = make_float4(0.f, 0.f, 0.f, 0.f);
#pragma unroll 8
    for (int k = 0; k < kH; ++k) {
      float w = wrow[k];
      float4 v = *reinterpret_cast<const float4*>(sh_g + k * kS + sq * 4);
      acc.x = fmaf(w, v.x, acc.x); acc.y = fmaf(w, v.y, acc.y);
      acc.z = fmaf(w, v.z, acc.z); acc.w = fmaf(w, v.w, acc.w);
    }
#pragma unroll 8
    for (int k = 0; k < kH; ++k) {
      float w = wrow[dh_off + k];
      float4 v = *reinterpret_cast<const float4*>(dh_g + k * kS + sq * 4);
      acc.x = fmaf(w, v.x, acc.x); acc.y = fmaf(w, v.y, acc.y);
      acc.z = fmaf(w, v.z, acc.z); acc.w = fmaf(w, v.w, acc.w);
    }
    *reinterpret_cast<float4*>(dst + h * kS + sq * 4) = acc;
  }
}

// ---------------- main sequential kernel ----------------

__global__ __launch_bounds__(512, 2) void ptrnet_main(
    const float* __restrict__ stat_g, const float* __restrict__ dyn_g,
    const float* __restrict__ vv1_g, const float* __restrict__ vv2_g,
    const float* __restrict__ bhh_g, const float* __restrict__ Whh_g,
    const float* __restrict__ ws, float* __restrict__ out) {
  extern __shared__ float sm[];
  const int b = blockIdx.x;
  const int tid = threadIdx.x;
  const int hh = tid & 127;          // output/s index
  const int seg = tid >> 7;          // 0..3: 32-wide k/h chunk
  const int lane = tid & 63;
  const int li = seg * 32 + (hh & 31);  // this thread's "owned" 128-index

  float* base1_l = sm + L_BASE1;
  float* base2_l = sm + L_BASE2;
  float* wct_l   = sm + L_WCT;
  float* bc_l    = sm + L_BC;
  float* bh_l    = sm + L_BH;
  float* stat_l  = sm + L_STAT;
  float* pg_l    = sm + L_PG;
  float* pu_l    = sm + L_PU;
  float* pa_l    = sm + L_PA;
  float* mask_l  = sm + L_MASK;
  float* dec_l   = sm + L_DEC;
  float* wsum_l  = sm + L_WSUM;
  float* rinv_l  = sm + L_RINV;

  // ---- LDS init (one-time) ----
  {
    const float4* b1g = reinterpret_cast<const float4*>(ws + OFF_BASE1 + (size_t)b * kH * kS);
    const float4* b2g = reinterpret_cast<const float4*>(ws + OFF_BASE2 + (size_t)b * kH * kS);
    float4* b1l = reinterpret_cast<float4*>(base1_l);
    float4* b2l = reinterpret_cast<float4*>(base2_l);
    for (int i = tid; i < kH * kS / 4; i += 512) { b1l[i] = b1g[i]; b2l[i] = b2g[i]; }
    for (int i = tid; i < kSS * kG3; i += 512) wct_l[i] = ws[OFF_WCT + i];
    if (tid < kG3) { bc_l[tid] = ws[OFF_BCOMB + tid]; bh_l[tid] = bhh_g[tid]; }
    for (int i = tid; i < kSS * kS; i += 512) stat_l[i] = stat_g[(size_t)b * kSS * kS + i];
    if (tid < kS)
      mask_l[tid] = (tid == 0 || dyn_g[(size_t)b * kDS * kS + tid] != 0.f) ? 0.f : 1.f;
    if (tid < kSS) dec_l[tid] = 0.f;
  }

  // ---- persistent register state (~20 VGPRs + pointers) ----
  float v_vv1 = vv1_g[li], v_vv2 = vv2_g[li];
  float h_prev = 0.f;

  // streamed base pointers
  const float* whp0 = Whh_g + (size_t)(0 * kH + hh) * kH + seg * 32;  // gate r row hh
  const float* whp1 = whp0 + (size_t)kH * kH;                          // gate z
  const float* whp2 = whp1 + (size_t)kH * kH;                          // gate n
  const float* w1p = ws + OFF_W1HT + (size_t)(seg * 32) * kH + hh;
  const float* w2p = ws + OFF_W2DT + (size_t)(seg * 32) * kH + hh;
  const float* shp = ws + OFF_SHT + (size_t)b * kS * kH + (size_t)(seg * 32) * kH + hh;
  __syncthreads();

  for (int t = 0; t < kT; ++t) {
    // ---- PH_A: gi (own li, kept in regs) + gh partials (Whh streamed) ----
    float gi0, gi1, gi2;
    {
      float4 q0[8], q1[8];
#pragma unroll
      for (int j = 0; j < 8; ++j) q0[j] = *reinterpret_cast<const float4*>(whp0 + 4 * j);
#pragma unroll
      for (int j = 0; j < 8; ++j) q1[j] = *reinterpret_cast<const float4*>(whp1 + 4 * j);
      // gi from LDS — overlaps the Whh load latency
      float v_dec = dec_l[lane & 7];
      gi0 = bc_l[li]; gi1 = bc_l[kH + li]; gi2 = bc_l[2 * kH + li];
#pragma unroll
      for (int i = 0; i < 8; ++i) {
        float d = rlane(v_dec, i);
        gi0 = fmaf(wct_l[i * kG3 + li], d, gi0);
        gi1 = fmaf(wct_l[i * kG3 + kH + li], d, gi1);
        gi2 = fmaf(wct_l[i * kG3 + 2 * kH + li], d, gi2);
      }
      float a0 = 0.f, a1 = 0.f;
#pragma unroll
      for (int j = 0; j < 8; ++j) {
        float4 w0 = q0[j], w1 = q1[j];
        float h0 = rlane(h_prev, 4 * j + 0), h1 = rlane(h_prev, 4 * j + 1);
        float h2 = rlane(h_prev, 4 * j + 2), h3 = rlane(h_prev, 4 * j + 3);
        a0 = fmaf(h0, w0.x, a0); a1 = fmaf(h0, w1.x, a1);
        a0 = fmaf(h1, w0.y, a0); a1 = fmaf(h1, w1.y, a1);
        a0 = fmaf(h2, w0.z, a0); a1 = fmaf(h2, w1.z, a1);
        a0 = fmaf(h3, w0.w, a0); a1 = fmaf(h3, w1.w, a1);
      }
#pragma unroll
      for (int j = 0; j < 8; ++j) q0[j] = *reinterpret_cast<const float4*>(whp2 + 4 * j);
      float a2x = 0.f, a2y = 0.f;
#pragma unroll
      for (int j = 0; j < 8; ++j) {
        float4 w = q0[j];
        a2x = fmaf(rlane(h_prev, 4 * j + 0), w.x, a2x);
        a2y = fmaf(rlane(h_prev, 4 * j + 1), w.y, a2y);
        a2x = fmaf(rlane(h_prev, 4 * j + 2), w.z, a2x);
        a2y = fmaf(rlane(h_prev, 4 * j + 3), w.w, a2y);
      }
      pg_l[(seg * 3 + 0) * kS + hh] = a0;
      pg_l[(seg * 3 + 1) * kS + hh] = a1;
      pg_l[(seg * 3 + 2) * kS + hh] = a2x + a2y;
    }
    __syncthreads();

    // ---- PH_B: GRU (replicated per-thread) + u1 partials (w1h streamed) ----
    {
      float b0[8], b1[8], b2[8], b3[8];
#pragma unroll
      for (int j = 0; j < 8; ++j) b0[j] = w1p[j * kH];
#pragma unroll
      for (int j = 0; j < 8; ++j) b1[j] = w1p[(8 + j) * kH];
#pragma unroll
      for (int j = 0; j < 8; ++j) b2[j] = w1p[(16 + j) * kH];
#pragma unroll
      for (int j = 0; j < 8; ++j) b3[j] = w1p[(24 + j) * kH];
      float gh0 = bh_l[li] +
          ((pg_l[(0*3+0)*kS+li] + pg_l[(1*3+0)*kS+li]) + (pg_l[(2*3+0)*kS+li] + pg_l[(3*3+0)*kS+li]));
      float gh1 = bh_l[kH + li] +
          ((pg_l[(0*3+1)*kS+li] + pg_l[(1*3+1)*kS+li]) + (pg_l[(2*3+1)*kS+li] + pg_l[(3*3+1)*kS+li]));
      float gh2 = bh_l[2*kH + li] +
          ((pg_l[(0*3+2)*kS+li] + pg_l[(1*3+2)*kS+li]) + (pg_l[(2*3+2)*kS+li] + pg_l[(3*3+2)*kS+li]));
      float r = 1.f / (1.f + __expf(-(gi0 + gh0)));
      float z = 1.f / (1.f + __expf(-(gi1 + gh1)));
      float x = gi2 + r * gh2;
      x = fminf(15.f, fmaxf(-15.f, x));
      float e = __expf(-2.f * x);
      float n = (1.f - e) / (1.f + e);
      float hnew = (1.f - z) * n + z * h_prev;
      h_prev = hnew;
      float acc0 = 0.f, acc1 = 0.f;
#pragma unroll
      for (int j = 0; j < 8; ++j) {
        acc0 = fmaf(rlane(hnew, j), b0[j], acc0);
        acc1 = fmaf(rlane(hnew, 8 + j), b1[j], acc1);
      }
#pragma unroll
      for (int j = 0; j < 8; ++j) {
        acc0 = fmaf(rlane(hnew, 16 + j), b2[j], acc0);
        acc1 = fmaf(rlane(hnew, 24 + j), b3[j], acc1);
      }
      pu_l[seg * kS + hh] = acc0 + acc1;
    }
    __syncthreads();

    // ---- PH_C: attn1 partials (tanh over 32 h-rows, base1 in LDS) ----
    {
      float v_u1 = (pu_l[li] + pu_l[kS + li]) + (pu_l[2*kS + li] + pu_l[3*kS + li]);
      float acc0 = 0.f, acc1 = 0.f;
#pragma unroll
      for (int kk = 0; kk < 16; ++kk) {
        float xa = base1_l[(seg * 32 + 2*kk) * kS + hh] + rlane(v_u1, 2*kk);
        float xb = base1_l[(seg * 32 + 2*kk+1) * kS + hh] + rlane(v_u1, 2*kk+1);
        acc0 = fmaf(rlane(v_vv1, 2*kk), tanh_fast(xa), acc0);
        acc1 = fmaf(rlane(v_vv1, 2*kk+1), tanh_fast(xb), acc1);
      }
      pa_l[seg * kS + hh] = acc0 + acc1;
    }
    __syncthreads();

    // ---- PH_E: softmax1 exp + chunk sums + dytext partials (static_h streamed) ----
    {
      float b0[8], b1[8], b2[8], b3[8];
#pragma unroll
      for (int j = 0; j < 8; ++j) b0[j] = shp[j * kH];
#pragma unroll
      for (int j = 0; j < 8; ++j) b1[j] = shp[(8 + j) * kH];
#pragma unroll
      for (int j = 0; j < 8; ++j) b2[j] = shp[(16 + j) * kH];
#pragma unroll
      for (int j = 0; j < 8; ++j) b3[j] = shp[(24 + j) * kH];
      float a = (pa_l[li] + pa_l[kS + li]) + (pa_l[2*kS + li] + pa_l[3*kS + li]);
      float ee = __expf(fminf(a, 60.f));
      float ssum = ee;
#pragma unroll
      for (int off = 1; off < 32; off <<= 1) ssum += __shfl_xor(ssum, off);
      if ((lane & 31) == 0) wsum_l[seg] = ssum;
      float acc0 = 0.f, acc1 = 0.f;
#pragma unroll
      for (int j = 0; j < 8; ++j) {
        acc0 = fmaf(rlane(ee, j), b0[j], acc0);
        acc1 = fmaf(rlane(ee, 8 + j), b1[j], acc1);
      }
#pragma unroll
      for (int j = 0; j < 8; ++j) {
        acc0 = fmaf(rlane(ee, 16 + j), b2[j], acc0);
        acc1 = fmaf(rlane(ee, 24 + j), b3[j], acc1);
      }
      pu_l[seg * kS + hh] = acc0 + acc1;
    }
    __syncthreads();

    // ---- PH_F: u2 partials (w2d streamed); one thread computes 1/sum ----
    {
      float b0[8], b1[8], b2[8], b3[8];
#pragma unroll
      for (int j = 0; j < 8; ++j) b0[j] = w2p[j * kH];
#pragma unroll
      for (int j = 0; j < 8; ++j) b1[j] = w2p[(8 + j) * kH];
#pragma unroll
      for (int j = 0; j < 8; ++j) b2[j] = w2p[(16 + j) * kH];
#pragma unroll
      for (int j = 0; j < 8; ++j) b3[j] = w2p[(24 + j) * kH];
      float v_dy = (pu_l[li] + pu_l[kS + li]) + (pu_l[2*kS + li] + pu_l[3*kS + li]);
      float acc0 = 0.f, acc1 = 0.f;
#pragma unroll
      for (int j = 0; j < 8; ++j) {
        acc0 = fmaf(rlane(v_dy, j), b0[j], acc0);
        acc1 = fmaf(rlane(v_dy, 8 + j), b1[j], acc1);
      }
#pragma unroll
      for (int j = 0; j < 8; ++j) {
        acc0 = fmaf(rlane(v_dy, 16 + j), b2[j], acc0);
        acc1 = fmaf(rlane(v_dy, 24 + j), b3[j], acc1);
      }
      pa_l[seg * kS + hh] = acc0 + acc1;
      if (tid == 0) rinv_l[0] = 1.0f / ((wsum_l[0] + wsum_l[1]) + (wsum_l[2] + wsum_l[3]));
    }
    __syncthreads();

    // ---- PH_G: attn2 partials (tanh over 32 h-rows, base2 in LDS) ----
    {
      float rin = rinv_l[0];
      float v_u2 = ((pa_l[li] + pa_l[kS + li]) + (pa_l[2*kS + li] + pa_l[3*kS + li])) * rin;
      float acc0 = 0.f, acc1 = 0.f;
#pragma unroll
      for (int kk = 0; kk < 16; ++kk) {
        float xa = base2_l[(seg * 32 + 2*kk) * kS + hh] + rlane(v_u2, 2*kk);
        float xb = base2_l[(seg * 32 + 2*kk+1) * kS + hh] + rlane(v_u2, 2*kk+1);
        acc0 = fmaf(rlane(v_vv2, 2*kk), tanh_fast(xa), acc0);
        acc1 = fmaf(rlane(v_vv2, 2*kk+1), tanh_fast(xb), acc1);
      }
      pu_l[seg * kS + hh] = acc0 + acc1;
    }
    __syncthreads();

    // ---- PH_H: logits, argmax, logsumexp, state update (wave 0 only) ----
    if (tid < 64) {
      int s0 = lane, s1 = lane + 64;
      float l0 = (pu_l[s0] + pu_l[kS + s0]) + (pu_l[2*kS + s0] + pu_l[3*kS + s0]);
      float l1 = (pu_l[s1] + pu_l[kS + s1]) + (pu_l[2*kS + s1] + pu_l[3*kS + s1]);
      l0 += (mask_l[s0] > 0.f ? 0.f : -1e30f);
      l1 += (mask_l[s1] > 0.f ? 0.f : -1e30f);
      float es = __expf(l0) + __expf(l1);
      float mv; int mi;
      if (l1 > l0) { mv = l1; mi = s1; } else { mv = l0; mi = s0; }
#pragma unroll
      for (int off = 1; off < 64; off <<= 1) {
        float ov = __shfl_xor(mv, off);
        int oi = __shfl_xor(mi, off);
        if (ov > mv || (ov == mv && oi < mi)) { mv = ov; mi = oi; }
        es += __shfl_xor(es, off);
      }
      if (lane == 0) {
        out[b * kT + t] = (float)mi;
        out[kB * kT + b * kT + t] = mv - __logf(es);
        mask_l[mi] = 0.f;
      }
      if (lane < kSS) dec_l[lane] = stat_l[lane * kS + mi];
    }
    __syncthreads();
  }
}

}  // namespace

extern "C" void kernel_launch(void* const* d_in, const int* in_sizes, int n_in,
                              void* d_out, int out_size, void* d_ws, size_t ws_size,
                              hipStream_t stream) {
  const float* stat_g = (const float*)d_in[0];
  const float* dyn_g  = (const float*)d_in[1];
  const float* W_s   = (const float*)d_in[3];
  const float* b_s   = (const float*)d_in[4];
  const float* W_d   = (const float*)d_in[5];
  const float* b_d   = (const float*)d_in[6];
  const float* W_dec = (const float*)d_in[7];
  const float* b_dec = (const float*)d_in[8];
  const float* vv1   = (const float*)d_in[9];
  const float* ww1   = (const float*)d_in[10];
  const float* vv2   = (const float*)d_in[11];
  const float* ww2   = (const float*)d_in[12];
  const float* W_ih  = (const float*)d_in[13];
  const float* W_hh  = (const float*)d_in[14];
  const float* b_ih  = (const float*)d_in[15];
  const float* b_hh  = (const float*)d_in[16];

  float* ws = (float*)d_ws;
  float* out = (float*)d_out;

  hipFuncSetAttribute(reinterpret_cast<const void*>(ptrnet_main),
                      hipFuncAttributeMaxDynamicSharedMemorySize, LDS_BYTES);

  prep_w<<<1, 256, 0, stream>>>(W_ih, W_dec, b_ih, b_dec, ww1, ww2, ws);
  prep_sh<<<kB, 256, 0, stream>>>(stat_g, dyn_g, W_s, b_s, W_d, b_d, ws);
  prep_base<<<dim3(kB, 2), 256, 0, stream>>>(ww1, ww2, ws);
  ptrnet_main<<<kB, 512, LDS_BYTES, stream>>>(stat_g, dyn_g, vv1, vv2, b_hh, W_hh, ws, out);
}